// Round 1
// baseline (268.537 us; speedup 1.0000x reference)
//
#include <hip/hip_runtime.h>

#define RES 64
#define FDIM 32
#define PLANE_ELEMS (FDIM * RES * RES)  // 131072 floats = 512 KB per plane

// ---------------------------------------------------------------------------
// Kernel 1: transpose the three [C,H,W] planes into one [3][H,W,C] buffer in
// d_ws so that all 32 channels at a given (y,x) are a contiguous 128B region.
// Total 1.5 MB — negligible cost, L2-resident afterwards.
// ---------------------------------------------------------------------------
__global__ void transpose_planes_kernel(const float* __restrict__ p0,
                                        const float* __restrict__ p1,
                                        const float* __restrict__ p2,
                                        float* __restrict__ out) {
    int i = blockIdx.x * blockDim.x + threadIdx.x;
    if (i >= 3 * PLANE_ELEMS) return;
    int p  = i / PLANE_ELEMS;
    int r  = i - p * PLANE_ELEMS;
    int c  = r & (FDIM - 1);   // output channel (fastest dim)
    int yx = r >> 5;           // y*RES + x
    const float* in = (p == 0) ? p0 : (p == 1) ? p1 : p2;
    out[i] = in[c * (RES * RES) + yx];
}

// align_corners=True bilinear coord helper (matches the reference exactly:
// clip g to [-1,1], u = (g+1)*0.5*(RES-1), floor, clamp indices to border)
__device__ __forceinline__ void grid_coord(float g, int& i0, int& i1, float& w) {
    g = fminf(fmaxf(g, -1.0f), 1.0f);
    float u = (g + 1.0f) * 0.5f * (float)(RES - 1);
    float f = floorf(u);
    w = u - f;
    int ii = (int)f;
    ii = ii < 0 ? 0 : (ii > RES - 1 ? RES - 1 : ii);
    i0 = ii;
    i1 = ii + 1 > RES - 1 ? RES - 1 : ii + 1;
}

__device__ __forceinline__ float4 bilerp4(float4 v00, float4 v01, float4 v10,
                                          float4 v11, float wx, float wy) {
    float4 r;
    float top, bot;
    top = v00.x * (1.0f - wx) + v01.x * wx;
    bot = v10.x * (1.0f - wx) + v11.x * wx;
    r.x = top * (1.0f - wy) + bot * wy;
    top = v00.y * (1.0f - wx) + v01.y * wx;
    bot = v10.y * (1.0f - wx) + v11.y * wx;
    r.y = top * (1.0f - wy) + bot * wy;
    top = v00.z * (1.0f - wx) + v01.z * wx;
    bot = v10.z * (1.0f - wx) + v11.z * wx;
    r.z = top * (1.0f - wy) + bot * wy;
    top = v00.w * (1.0f - wx) + v01.w * wx;
    bot = v10.w * (1.0f - wx) + v11.w * wx;
    r.w = top * (1.0f - wy) + bot * wy;
    return r;
}

// ---------------------------------------------------------------------------
// Kernel 2 (fast path): 8 threads per point; thread cg handles channels
// [4cg, 4cg+4) of all 3 planes. Planes in [H,W,C] layout -> every corner
// read is one float4; every store is one float4. Per wave: 8 points, all
// stores land in a contiguous 3 KB span of the output.
// ---------------------------------------------------------------------------
__global__ __launch_bounds__(256) void kplanes_sample_hwc(
    const float* __restrict__ xyz,
    const float* __restrict__ planes_t,  // [3][RES][RES][FDIM]
    float* __restrict__ out, int N) {
    int tid = blockIdx.x * blockDim.x + threadIdx.x;
    int pt = tid >> 3;
    int cg = tid & 7;
    if (pt >= N) return;

    float gx = xyz[pt * 3 + 0];
    float gy = xyz[pt * 3 + 1];
    float gz = xyz[pt * 3 + 2];

    int x0, x1, y0, y1, z0, z1;
    float wx, wy, wz;
    grid_coord(gx, x0, x1, wx);
    grid_coord(gy, y0, y1, wy);
    grid_coord(gz, z0, z1, wz);

    const float4* P = (const float4*)planes_t;  // plane stride = 32768 float4
    float4* o = (float4*)out;                    // row stride = 24 float4
    long long orow = (long long)pt * 24 + cg;

    // plane_xy: gx -> width(x), gy -> height(y)
    {
        const float4* B = P;  // plane 0
        float4 v00 = B[(y0 * RES + x0) * 8 + cg];
        float4 v01 = B[(y0 * RES + x1) * 8 + cg];
        float4 v10 = B[(y1 * RES + x0) * 8 + cg];
        float4 v11 = B[(y1 * RES + x1) * 8 + cg];
        o[orow] = bilerp4(v00, v01, v10, v11, wx, wy);
    }
    // plane_xz: gx -> width(x), gz -> height(y)
    {
        const float4* B = P + 32768;  // plane 1
        float4 v00 = B[(z0 * RES + x0) * 8 + cg];
        float4 v01 = B[(z0 * RES + x1) * 8 + cg];
        float4 v10 = B[(z1 * RES + x0) * 8 + cg];
        float4 v11 = B[(z1 * RES + x1) * 8 + cg];
        o[orow + 8] = bilerp4(v00, v01, v10, v11, wx, wz);
    }
    // plane_yz: gy -> width(x), gz -> height(y)
    {
        const float4* B = P + 65536;  // plane 2
        float4 v00 = B[(z0 * RES + y0) * 8 + cg];
        float4 v01 = B[(z0 * RES + y1) * 8 + cg];
        float4 v10 = B[(z1 * RES + y0) * 8 + cg];
        float4 v11 = B[(z1 * RES + y1) * 8 + cg];
        o[orow + 16] = bilerp4(v00, v01, v10, v11, wy, wz);
    }
}

// ---------------------------------------------------------------------------
// Fallback (if ws too small): sample directly from [C,H,W] layout with
// scalar loads. Correct but slower (channel gather).
// ---------------------------------------------------------------------------
__global__ __launch_bounds__(256) void kplanes_sample_chw(
    const float* __restrict__ xyz,
    const float* __restrict__ pxy,
    const float* __restrict__ pxz,
    const float* __restrict__ pyz,
    float* __restrict__ out, int N) {
    int tid = blockIdx.x * blockDim.x + threadIdx.x;
    int pt = tid >> 3;
    int cg = tid & 7;
    if (pt >= N) return;

    float gx = xyz[pt * 3 + 0];
    float gy = xyz[pt * 3 + 1];
    float gz = xyz[pt * 3 + 2];

    int x0, x1, y0, y1, z0, z1;
    float wx, wy, wz;
    grid_coord(gx, x0, x1, wx);
    grid_coord(gy, y0, y1, wy);
    grid_coord(gz, z0, z1, wz);

    long long obase = (long long)pt * 96 + cg * 4;

    const float* planes[3] = {pxy, pxz, pyz};
    int a0[3] = {y0 * RES + x0, z0 * RES + x0, z0 * RES + y0};
    int a1[3] = {y0 * RES + x1, z0 * RES + x1, z0 * RES + y1};
    int a2[3] = {y1 * RES + x0, z1 * RES + x0, z1 * RES + y0};
    int a3[3] = {y1 * RES + x1, z1 * RES + x1, z1 * RES + y1};
    float wwx[3] = {wx, wx, wy};
    float wwy[3] = {wy, wz, wz};

#pragma unroll
    for (int p = 0; p < 3; ++p) {
        const float* B = planes[p];
#pragma unroll
        for (int k = 0; k < 4; ++k) {
            int c = cg * 4 + k;
            const float* Bc = B + c * (RES * RES);
            float v00 = Bc[a0[p]];
            float v01 = Bc[a1[p]];
            float v10 = Bc[a2[p]];
            float v11 = Bc[a3[p]];
            float top = v00 * (1.0f - wwx[p]) + v01 * wwx[p];
            float bot = v10 * (1.0f - wwx[p]) + v11 * wwx[p];
            out[obase + p * 32 + k] = top * (1.0f - wwy[p]) + bot * wwy[p];
        }
    }
}

extern "C" void kernel_launch(void* const* d_in, const int* in_sizes, int n_in,
                              void* d_out, int out_size, void* d_ws, size_t ws_size,
                              hipStream_t stream) {
    const float* xyz = (const float*)d_in[0];
    const float* pxy = (const float*)d_in[1];
    const float* pxz = (const float*)d_in[2];
    const float* pyz = (const float*)d_in[3];
    float* out = (float*)d_out;
    int N = in_sizes[0] / 3;

    size_t need = (size_t)3 * PLANE_ELEMS * sizeof(float);  // 1.5 MB
    long long total = (long long)N * 8;
    int grid = (int)((total + 255) / 256);

    if (ws_size >= need) {
        float* ws = (float*)d_ws;
        transpose_planes_kernel<<<(3 * PLANE_ELEMS + 255) / 256, 256, 0, stream>>>(
            pxy, pxz, pyz, ws);
        kplanes_sample_hwc<<<grid, 256, 0, stream>>>(xyz, ws, out, N);
    } else {
        kplanes_sample_chw<<<grid, 256, 0, stream>>>(xyz, pxy, pxz, pyz, out, N);
    }
}

// Round 2
// 145.756 us; speedup vs baseline: 1.8424x; 1.8424x over previous
//
#include <hip/hip_runtime.h>
#include <hip/hip_bf16.h>

#define RES 64
#define FDIM 32
#define PLANE_ELEMS (FDIM * RES * RES)  // 131072 elems per plane

typedef float vfloat4 __attribute__((ext_vector_type(4)));

// ---------------------------------------------------------------------------
// Kernel 1: transpose+quantize the three [C,H,W] f32 planes into one
// [3][H][W][C] bf16 buffer in d_ws. 768 KB total -> stays L2-resident.
// Each (y,x) cell is a contiguous 64 B run of 32 bf16 channels; adjacent
// x-cells share a 128 B cache line.
// ---------------------------------------------------------------------------
__global__ void transpose_planes_bf16(const float* __restrict__ p0,
                                      const float* __restrict__ p1,
                                      const float* __restrict__ p2,
                                      __hip_bfloat16* __restrict__ out) {
    int i = blockIdx.x * blockDim.x + threadIdx.x;
    if (i >= 3 * PLANE_ELEMS) return;
    int p  = i / PLANE_ELEMS;
    int r  = i - p * PLANE_ELEMS;
    int c  = r & (FDIM - 1);   // output channel (fastest dim)
    int yx = r >> 5;           // y*RES + x
    const float* in = (p == 0) ? p0 : (p == 1) ? p1 : p2;
    out[i] = __float2bfloat16(in[c * (RES * RES) + yx]);
}

// align_corners=True bilinear coord helper (matches reference exactly)
__device__ __forceinline__ void grid_coord(float g, int& i0, int& i1, float& w) {
    g = fminf(fmaxf(g, -1.0f), 1.0f);
    float u = (g + 1.0f) * 0.5f * (float)(RES - 1);
    float f = floorf(u);
    w = u - f;
    int ii = (int)f;
    ii = ii < 0 ? 0 : (ii > RES - 1 ? RES - 1 : ii);
    i0 = ii;
    i1 = ii + 1 > RES - 1 ? RES - 1 : ii + 1;
}

// decode 4 bf16 (packed in uint2, memory order ch0..ch3) to f32
__device__ __forceinline__ vfloat4 dec4(uint2 w) {
    vfloat4 f;
    f.x = __uint_as_float(w.x << 16);
    f.y = __uint_as_float(w.x & 0xffff0000u);
    f.z = __uint_as_float(w.y << 16);
    f.w = __uint_as_float(w.y & 0xffff0000u);
    return f;
}

__device__ __forceinline__ vfloat4 bilerp4(uint2 w00, uint2 w01, uint2 w10,
                                           uint2 w11, float wx, float wy) {
    vfloat4 v00 = dec4(w00), v01 = dec4(w01), v10 = dec4(w10), v11 = dec4(w11);
    float iwx = 1.0f - wx, iwy = 1.0f - wy;
    vfloat4 top = v00 * iwx + v01 * wx;
    vfloat4 bot = v10 * iwx + v11 * wx;
    return top * iwy + bot * wy;
}

// ---------------------------------------------------------------------------
// Kernel 2: 8 threads/point; thread cg handles channels [4cg,4cg+4) of all
// 3 planes. Corner read = 8 B (uint2 of 4 bf16); per wave-instr: 8 points x
// 64 B contiguous segments. Store = one float4 per plane; per wave-instr:
// 8 x 128 B contiguous segments. Output stores are nontemporal so the
// 768 MB write stream doesn't evict the 768 KB plane working set from L2.
// ---------------------------------------------------------------------------
__global__ __launch_bounds__(256) void kplanes_sample_bf16(
    const float* __restrict__ xyz,
    const __hip_bfloat16* __restrict__ planes_t,  // [3][RES][RES][FDIM] bf16
    float* __restrict__ out, int N) {
    int tid = blockIdx.x * blockDim.x + threadIdx.x;
    int pt = tid >> 3;
    int cg = tid & 7;
    if (pt >= N) return;

    float gx = xyz[pt * 3 + 0];
    float gy = xyz[pt * 3 + 1];
    float gz = xyz[pt * 3 + 2];

    int x0, x1, y0, y1, z0, z1;
    float wx, wy, wz;
    grid_coord(gx, x0, x1, wx);
    grid_coord(gy, y0, y1, wy);
    grid_coord(gz, z0, z1, wz);

    // cell = 64 B = 8 uint2; corner uint2 index = (p*4096 + y*64 + x)*8 + cg
    const uint2* P = (const uint2*)planes_t;
    vfloat4* o = (vfloat4*)out;  // row stride = 24 float4
    long long orow = (long long)pt * 24 + cg;

    // plane_xy: gx -> width, gy -> height
    {
        uint2 w00 = P[(y0 * RES + x0) * 8 + cg];
        uint2 w01 = P[(y0 * RES + x1) * 8 + cg];
        uint2 w10 = P[(y1 * RES + x0) * 8 + cg];
        uint2 w11 = P[(y1 * RES + x1) * 8 + cg];
        vfloat4 r = bilerp4(w00, w01, w10, w11, wx, wy);
        __builtin_nontemporal_store(r, &o[orow]);
    }
    // plane_xz: gx -> width, gz -> height
    {
        const uint2* B = P + 4096 * 8;
        uint2 w00 = B[(z0 * RES + x0) * 8 + cg];
        uint2 w01 = B[(z0 * RES + x1) * 8 + cg];
        uint2 w10 = B[(z1 * RES + x0) * 8 + cg];
        uint2 w11 = B[(z1 * RES + x1) * 8 + cg];
        vfloat4 r = bilerp4(w00, w01, w10, w11, wx, wz);
        __builtin_nontemporal_store(r, &o[orow + 8]);
    }
    // plane_yz: gy -> width, gz -> height
    {
        const uint2* B = P + 2 * 4096 * 8;
        uint2 w00 = B[(z0 * RES + y0) * 8 + cg];
        uint2 w01 = B[(z0 * RES + y1) * 8 + cg];
        uint2 w10 = B[(z1 * RES + y0) * 8 + cg];
        uint2 w11 = B[(z1 * RES + y1) * 8 + cg];
        vfloat4 r = bilerp4(w00, w01, w10, w11, wy, wz);
        __builtin_nontemporal_store(r, &o[orow + 16]);
    }
}

// ---------------------------------------------------------------------------
// Fallback (ws too small): direct f32 [C,H,W] sampling, correct but slower.
// ---------------------------------------------------------------------------
__global__ __launch_bounds__(256) void kplanes_sample_chw(
    const float* __restrict__ xyz,
    const float* __restrict__ pxy,
    const float* __restrict__ pxz,
    const float* __restrict__ pyz,
    float* __restrict__ out, int N) {
    int tid = blockIdx.x * blockDim.x + threadIdx.x;
    int pt = tid >> 3;
    int cg = tid & 7;
    if (pt >= N) return;

    float gx = xyz[pt * 3 + 0];
    float gy = xyz[pt * 3 + 1];
    float gz = xyz[pt * 3 + 2];

    int x0, x1, y0, y1, z0, z1;
    float wx, wy, wz;
    grid_coord(gx, x0, x1, wx);
    grid_coord(gy, y0, y1, wy);
    grid_coord(gz, z0, z1, wz);

    long long obase = (long long)pt * 96 + cg * 4;

    const float* planes[3] = {pxy, pxz, pyz};
    int a0[3] = {y0 * RES + x0, z0 * RES + x0, z0 * RES + y0};
    int a1[3] = {y0 * RES + x1, z0 * RES + x1, z0 * RES + y1};
    int a2[3] = {y1 * RES + x0, z1 * RES + x0, z1 * RES + y0};
    int a3[3] = {y1 * RES + x1, z1 * RES + x1, z1 * RES + y1};
    float wwx[3] = {wx, wx, wy};
    float wwy[3] = {wy, wz, wz};

#pragma unroll
    for (int p = 0; p < 3; ++p) {
        const float* B = planes[p];
#pragma unroll
        for (int k = 0; k < 4; ++k) {
            int c = cg * 4 + k;
            const float* Bc = B + c * (RES * RES);
            float v00 = Bc[a0[p]];
            float v01 = Bc[a1[p]];
            float v10 = Bc[a2[p]];
            float v11 = Bc[a3[p]];
            float top = v00 * (1.0f - wwx[p]) + v01 * wwx[p];
            float bot = v10 * (1.0f - wwx[p]) + v11 * wwx[p];
            out[obase + p * 32 + k] = top * (1.0f - wwy[p]) + bot * wwy[p];
        }
    }
}

extern "C" void kernel_launch(void* const* d_in, const int* in_sizes, int n_in,
                              void* d_out, int out_size, void* d_ws, size_t ws_size,
                              hipStream_t stream) {
    const float* xyz = (const float*)d_in[0];
    const float* pxy = (const float*)d_in[1];
    const float* pxz = (const float*)d_in[2];
    const float* pyz = (const float*)d_in[3];
    float* out = (float*)d_out;
    int N = in_sizes[0] / 3;

    size_t need = (size_t)3 * PLANE_ELEMS * sizeof(__hip_bfloat16);  // 768 KB
    long long total = (long long)N * 8;
    int grid = (int)((total + 255) / 256);

    if (ws_size >= need) {
        __hip_bfloat16* ws = (__hip_bfloat16*)d_ws;
        transpose_planes_bf16<<<(3 * PLANE_ELEMS + 255) / 256, 256, 0, stream>>>(
            pxy, pxz, pyz, ws);
        kplanes_sample_bf16<<<grid, 256, 0, stream>>>(xyz, ws, out, N);
    } else {
        kplanes_sample_chw<<<grid, 256, 0, stream>>>(xyz, pxy, pxz, pyz, out, N);
    }
}